// Round 1
// baseline (525.145 us; speedup 1.0000x reference)
//
#include <hip/hip_runtime.h>
#include <math.h>

#define BATCH 32
#define CDIM  256
#define NDIM  1024
#define BN    (BATCH * NDIM)   // 32768
#define LN_EPSF 1e-5f
#define SCALE 0.0625f

// ---------------------------------------------------------------------------
// ws layout (floats):
//   [0 .. BN)        mu_x
//   [BN .. 2BN)      rinv_x
//   [2BN .. 3BN)     mu_y
//   [3BN .. 4BN)     rinv_y
//   [4BN ..)         Qt [B][C][N]  then  Kt [B][C][N]   (fp32, 32MB each)
// ---------------------------------------------------------------------------

// Kernel 1: per-(b,n) mean / rsqrt(var+eps) over the C axis (stride-N reads,
// consecutive lanes -> consecutive n -> coalesced).
__global__ __launch_bounds__(256) void stats_k(const float* __restrict__ x,
                                               const float* __restrict__ y,
                                               float* __restrict__ st) {
  int gid = blockIdx.x * 256 + threadIdx.x;   // 0 .. 2*BN
  int which = gid >> 15;                      // 0: x, 1: y
  int idx = gid & (BN - 1);
  int b = idx >> 10, n = idx & (NDIM - 1);
  const float* p = (which ? y : x) + ((size_t)b * CDIM) * NDIM + n;
  float s = 0.f, q = 0.f;
#pragma unroll 8
  for (int c = 0; c < CDIM; ++c) {
    float v = p[(size_t)c * NDIM];
    s += v;
    q += v * v;
  }
  float m = s * (1.f / CDIM);
  float var = fmaxf(q * (1.f / CDIM) - m * m, 0.f);
  float* dst = st + which * (2 * BN);
  dst[idx] = m;
  dst[BN + idx] = rsqrtf(var + LN_EPSF);
}

// Kernel 2: Out_t[b][co][n] = sum_c W[co][c]*LN(src[b][c][n]) + bias[co]
// 128x128 tile per block, K-slice 16, 8x8 per thread. LN fused into B-load.
// grid: (N/128, C/128, B*2)  z = b*2 + which
__global__ __launch_bounds__(256) void proj_k(const float* __restrict__ x,
                                              const float* __restrict__ y,
                                              const float* __restrict__ gamma,
                                              const float* __restrict__ beta,
                                              const float* __restrict__ Wq,
                                              const float* __restrict__ Wk,
                                              const float* __restrict__ bq,
                                              const float* __restrict__ bk,
                                              const float* __restrict__ st,
                                              float* __restrict__ qt) {
  __shared__ float As[16][132];   // As[c][co]  (W^T slice)
  __shared__ float Bs[16][132];   // Bs[c][n]   (LN'd src slice)
  __shared__ float gl[CDIM], bl[CDIM];

  const int n0  = blockIdx.x * 128;
  const int co0 = blockIdx.y * 128;
  const int bz  = blockIdx.z;
  const int b = bz >> 1, which = bz & 1;
  const float* src  = which ? y : x;
  const float* W    = which ? Wk : Wq;
  const float* bias = which ? bk : bq;
  const float* mu = st + which * (2 * BN) + b * NDIM;
  const float* ri = mu + BN;
  float* out = qt + (size_t)which * ((size_t)BATCH * CDIM * NDIM)
                  + ((size_t)b * CDIM) * NDIM;

  const int t = threadIdx.x;
  gl[t] = gamma[t];
  bl[t] = beta[t];

  const int n_l = t & 127;        // B-load col
  const int kr  = t >> 7;         // 0..1
  const int ac  = t & 15;         // A-load c
  const int ar  = t >> 4;         // A-load row base 0..15
  const int tx  = t & 15;         // compute col group
  const int ty  = t >> 4;         // compute row group

  const float mu_n = mu[n0 + n_l];
  const float ri_n = ri[n0 + n_l];

  float acc[8][8];
#pragma unroll
  for (int i = 0; i < 8; ++i)
#pragma unroll
    for (int j = 0; j < 8; ++j) acc[i][j] = 0.f;

  __syncthreads();   // gl/bl ready

  for (int kt = 0; kt < 16; ++kt) {
    const int c0 = kt * 16;
#pragma unroll
    for (int i = 0; i < 8; ++i) {
      As[ac][ar + 16 * i] = W[(size_t)(co0 + ar + 16 * i) * CDIM + c0 + ac];
    }
#pragma unroll
    for (int i = 0; i < 8; ++i) {
      const int k = kr * 8 + i;
      const int c = c0 + k;
      float v = src[((size_t)b * CDIM + c) * NDIM + n0 + n_l];
      Bs[k][n_l] = (v - mu_n) * ri_n * gl[c] + bl[c];
    }
    __syncthreads();
#pragma unroll
    for (int k = 0; k < 16; ++k) {
      float4 a0 = *(const float4*)&As[k][ty * 8];
      float4 a1 = *(const float4*)&As[k][ty * 8 + 4];
      float4 b0 = *(const float4*)&Bs[k][tx * 8];
      float4 b1 = *(const float4*)&Bs[k][tx * 8 + 4];
      float av[8] = {a0.x, a0.y, a0.z, a0.w, a1.x, a1.y, a1.z, a1.w};
      float bv[8] = {b0.x, b0.y, b0.z, b0.w, b1.x, b1.y, b1.z, b1.w};
#pragma unroll
      for (int i = 0; i < 8; ++i)
#pragma unroll
        for (int j = 0; j < 8; ++j) acc[i][j] += av[i] * bv[j];
    }
    __syncthreads();
  }

#pragma unroll
  for (int i = 0; i < 8; ++i) {
    const int co = co0 + ty * 8 + i;
    const float bi = bias[co];
    float* po = out + (size_t)co * NDIM + n0 + tx * 8;
#pragma unroll
    for (int j = 0; j < 8; ++j) po[j] = acc[i][j] + bi;
  }
}

// Kernel 3: scores = Qt^T Kt (over C), scale, online softmax over m, output
// only diag element's probability. 128 rows x 128-col m-tiles, 8x8/thread.
// grid: (N/128, B)
__global__ __launch_bounds__(256) void attn_k(const float* __restrict__ qt,
                                              float* __restrict__ outp) {
  __shared__ float Qs[16][132];
  __shared__ float Ks[16][132];
  __shared__ float diag[128];

  const int n0 = blockIdx.x * 128;
  const int b  = blockIdx.y;
  const float* Q = qt + ((size_t)b * CDIM) * NDIM;
  const float* K = qt + (size_t)BATCH * CDIM * NDIM + ((size_t)b * CDIM) * NDIM;

  const int t = threadIdx.x;
  const int n_l = t & 127;
  const int kr  = t >> 7;
  const int tx  = t & 15;
  const int ty  = t >> 4;

  float M[8], S[8];
#pragma unroll
  for (int i = 0; i < 8; ++i) { M[i] = -1e30f; S[i] = 0.f; }

  for (int mt = 0; mt < 8; ++mt) {
    const int m0 = mt * 128;
    float acc[8][8];
#pragma unroll
    for (int i = 0; i < 8; ++i)
#pragma unroll
      for (int j = 0; j < 8; ++j) acc[i][j] = 0.f;

    for (int kt = 0; kt < 16; ++kt) {
      const int c0 = kt * 16;
#pragma unroll
      for (int i = 0; i < 8; ++i) {
        const int k = kr * 8 + i;
        Qs[k][n_l] = Q[(size_t)(c0 + k) * NDIM + n0 + n_l];
        Ks[k][n_l] = K[(size_t)(c0 + k) * NDIM + m0 + n_l];
      }
      __syncthreads();
#pragma unroll
      for (int k = 0; k < 16; ++k) {
        float4 a0 = *(const float4*)&Qs[k][ty * 8];
        float4 a1 = *(const float4*)&Qs[k][ty * 8 + 4];
        float4 b0 = *(const float4*)&Ks[k][tx * 8];
        float4 b1 = *(const float4*)&Ks[k][tx * 8 + 4];
        float av[8] = {a0.x, a0.y, a0.z, a0.w, a1.x, a1.y, a1.z, a1.w};
        float bv[8] = {b0.x, b0.y, b0.z, b0.w, b1.x, b1.y, b1.z, b1.w};
#pragma unroll
        for (int i = 0; i < 8; ++i)
#pragma unroll
          for (int j = 0; j < 8; ++j) acc[i][j] += av[i] * bv[j];
      }
      __syncthreads();
    }

    // scale + online softmax update (rows spread over 16 lanes tx)
#pragma unroll
    for (int i = 0; i < 8; ++i) {
#pragma unroll
      for (int j = 0; j < 8; ++j) acc[i][j] *= SCALE;

      float tmax = acc[i][0];
#pragma unroll
      for (int j = 1; j < 8; ++j) tmax = fmaxf(tmax, acc[i][j]);
#pragma unroll
      for (int o = 8; o >= 1; o >>= 1) tmax = fmaxf(tmax, __shfl_xor(tmax, o));
      const float Mn = fmaxf(M[i], tmax);
      float ps = 0.f;
#pragma unroll
      for (int j = 0; j < 8; ++j) ps += __expf(acc[i][j] - Mn);
#pragma unroll
      for (int o = 8; o >= 1; o >>= 1) ps += __shfl_xor(ps, o);
      S[i] = S[i] * __expf(M[i] - Mn) + ps;
      M[i] = Mn;
      if (mt == blockIdx.x && tx == ty) diag[ty * 8 + i] = acc[i][i];
    }
  }
  __syncthreads();   // diag visible to all

  if (tx == 0) {
#pragma unroll
    for (int i = 0; i < 8; ++i) {
      const int r = ty * 8 + i;
      outp[(size_t)b * NDIM + n0 + r] = __expf(diag[r] - M[i]) / S[i];
    }
  }
}

extern "C" void kernel_launch(void* const* d_in, const int* in_sizes, int n_in,
                              void* d_out, int out_size, void* d_ws, size_t ws_size,
                              hipStream_t stream) {
  (void)in_sizes; (void)n_in; (void)out_size; (void)ws_size;
  const float* x     = (const float*)d_in[0];
  const float* y     = (const float*)d_in[1];
  const float* gamma = (const float*)d_in[2];
  const float* beta  = (const float*)d_in[3];
  const float* Wq    = (const float*)d_in[4];
  const float* Wk    = (const float*)d_in[5];
  const float* bq    = (const float*)d_in[6];
  const float* bk    = (const float*)d_in[7];
  float* out = (float*)d_out;
  float* ws  = (float*)d_ws;

  float* st = ws;                    // 4*BN floats
  float* qt = ws + 4 * BN;           // 2*B*C*N floats

  stats_k<<<(2 * BN) / 256, 256, 0, stream>>>(x, y, st);

  dim3 g2(NDIM / 128, CDIM / 128, BATCH * 2);
  proj_k<<<g2, 256, 0, stream>>>(x, y, gamma, beta, Wq, Wk, bq, bk, st, qt);

  dim3 g3(NDIM / 128, BATCH);
  attn_k<<<g3, 256, 0, stream>>>(qt, out);
}

// Round 2
// 302.882 us; speedup vs baseline: 1.7338x; 1.7338x over previous
//
#include <hip/hip_runtime.h>
#include <math.h>

#define BATCH 32
#define CDIM  256
#define NDIM  1024
#define BN    (BATCH * NDIM)               // 32768
#define BNC   ((size_t)BATCH * NDIM * CDIM)
#define LN_EPSF 1e-5f
#define SCALE 0.0625f

typedef __attribute__((ext_vector_type(8))) __bf16 bf16x8;
typedef __attribute__((ext_vector_type(4))) float f32x4;
typedef __attribute__((ext_vector_type(8))) short short8;

static __device__ __forceinline__ unsigned short f2bf(float f) {
  unsigned u = __float_as_uint(f);
  unsigned r = (u + 0x7FFFu + ((u >> 16) & 1u)) >> 16;   // RNE
  return (unsigned short)r;
}
static __device__ __forceinline__ float bf2f(unsigned short h) {
  return __uint_as_float(((unsigned)h) << 16);
}
static __device__ __forceinline__ void gload16(const void* g, void* l) {
  __builtin_amdgcn_global_load_lds((const __attribute__((address_space(1))) void*)g,
                                   (__attribute__((address_space(3))) void*)l, 16, 0, 0);
}

// ---------------------------------------------------------------------------
// ws layout:
//   float st[4*BN]                      mu_x, rinv_x, mu_y, rinv_y
//   ushort planes[4*BNC]                qh, ql, kh, kl   each [B][N][C]
// ---------------------------------------------------------------------------

__global__ __launch_bounds__(256) void stats_k(const float* __restrict__ x,
                                               const float* __restrict__ y,
                                               float* __restrict__ st) {
  int gid = blockIdx.x * 256 + threadIdx.x;
  int which = gid >> 15;
  int idx = gid & (BN - 1);
  int b = idx >> 10, n = idx & (NDIM - 1);
  const float* p = (which ? y : x) + ((size_t)b * CDIM) * NDIM + n;
  float s = 0.f, q = 0.f;
#pragma unroll 8
  for (int c = 0; c < CDIM; ++c) {
    float v = p[(size_t)c * NDIM];
    s += v;
    q += v * v;
  }
  float m = s * (1.f / CDIM);
  float var = fmaxf(q * (1.f / CDIM) - m * m, 0.f);
  float* dst = st + which * (2 * BN);
  dst[idx] = m;
  dst[BN + idx] = rsqrtf(var + LN_EPSF);
}

// proj: fp32 reg-tile GEMM (unchanged math), epilogue emits [B][N][C] bf16
// hi/lo planes. grid: (N/128, C/128, B*2)
__global__ __launch_bounds__(256) void proj_k(const float* __restrict__ x,
                                              const float* __restrict__ y,
                                              const float* __restrict__ gamma,
                                              const float* __restrict__ beta,
                                              const float* __restrict__ Wq,
                                              const float* __restrict__ Wk,
                                              const float* __restrict__ bq,
                                              const float* __restrict__ bk,
                                              const float* __restrict__ st,
                                              unsigned short* __restrict__ planes) {
  __shared__ float As[16][132];
  __shared__ float Bs[16][132];
  __shared__ float gl[CDIM], bl[CDIM];

  const int n0  = blockIdx.x * 128;
  const int co0 = blockIdx.y * 128;
  const int bz  = blockIdx.z;
  const int b = bz >> 1, which = bz & 1;
  const float* src  = which ? y : x;
  const float* W    = which ? Wk : Wq;
  const float* bias = which ? bk : bq;
  const float* mu = st + which * (2 * BN) + b * NDIM;
  const float* ri = mu + BN;

  const int t = threadIdx.x;
  gl[t] = gamma[t];
  bl[t] = beta[t];

  const int n_l = t & 127;
  const int kr  = t >> 7;
  const int ac  = t & 15;
  const int ar  = t >> 4;
  const int tx  = t & 15;
  const int ty  = t >> 4;

  const float mu_n = mu[n0 + n_l];
  const float ri_n = ri[n0 + n_l];

  float acc[8][8];
#pragma unroll
  for (int i = 0; i < 8; ++i)
#pragma unroll
    for (int j = 0; j < 8; ++j) acc[i][j] = 0.f;

  __syncthreads();

  for (int kt = 0; kt < 16; ++kt) {
    const int c0 = kt * 16;
#pragma unroll
    for (int i = 0; i < 8; ++i) {
      As[ac][ar + 16 * i] = W[(size_t)(co0 + ar + 16 * i) * CDIM + c0 + ac];
    }
#pragma unroll
    for (int i = 0; i < 8; ++i) {
      const int k = kr * 8 + i;
      const int c = c0 + k;
      float v = src[((size_t)b * CDIM + c) * NDIM + n0 + n_l];
      Bs[k][n_l] = (v - mu_n) * ri_n * gl[c] + bl[c];
    }
    __syncthreads();
#pragma unroll
    for (int k = 0; k < 16; ++k) {
      float4 a0 = *(const float4*)&As[k][ty * 8];
      float4 a1 = *(const float4*)&As[k][ty * 8 + 4];
      float4 b0 = *(const float4*)&Bs[k][tx * 8];
      float4 b1 = *(const float4*)&Bs[k][tx * 8 + 4];
      float av[8] = {a0.x, a0.y, a0.z, a0.w, a1.x, a1.y, a1.z, a1.w};
      float bv[8] = {b0.x, b0.y, b0.z, b0.w, b1.x, b1.y, b1.z, b1.w};
#pragma unroll
      for (int i = 0; i < 8; ++i)
#pragma unroll
        for (int j = 0; j < 8; ++j) acc[i][j] += av[i] * bv[j];
    }
    __syncthreads();
  }

  // epilogue: split to bf16 hi/lo, layout [b][n][c]
  unsigned short* oh = planes + (size_t)which * (2 * BNC);
  unsigned short* ol = oh + BNC;
  float bias8[8];
#pragma unroll
  for (int i = 0; i < 8; ++i) bias8[i] = bias[co0 + ty * 8 + i];
#pragma unroll
  for (int j = 0; j < 8; ++j) {
    const int n = n0 + tx * 8 + j;
    size_t off = ((size_t)b * NDIM + n) * CDIM + co0 + ty * 8;
    short8 hs, ls;
#pragma unroll
    for (int i = 0; i < 8; ++i) {
      float v = acc[i][j] + bias8[i];
      unsigned short h = f2bf(v);
      hs[i] = (short)h;
      ls[i] = (short)f2bf(v - bf2f(h));
    }
    *(short8*)(oh + off) = hs;
    *(short8*)(ol + off) = ls;
  }
}

// attn: scores = Q K^T via 3-term split-bf16 MFMA, online softmax, diag out.
// 1D grid 512 blocks (batch-grouped XCD swizzle), 4 waves, 16 rows/wave.
__global__ __launch_bounds__(256) void attn_k(const unsigned short* __restrict__ planes,
                                              float* __restrict__ outp) {
  const unsigned short* qh = planes;
  const unsigned short* ql = planes + BNC;
  const unsigned short* kh = planes + 2 * BNC;
  const unsigned short* kl = planes + 3 * BNC;
  __shared__ unsigned short kbuf[2][2][4096];   // [dbuf][hi/lo][8KB]

  const int p = blockIdx.x;                      // 0..511
  const int b = (p & 7) * 4 + ((p >> 3) & 3);    // same-batch blocks -> same XCD
  const int n0 = (p >> 5) * 64;
  const int t = threadIdx.x;
  const int wid = t >> 6;
  const int l = t & 63;
  const int l15 = l & 15, l4 = l >> 4;

  // Q A-fragments for this wave's 16 rows, whole C: kept in registers.
  bf16x8 ah[8], al[8];
  {
    size_t rowbase = ((size_t)b * NDIM + n0 + wid * 16 + l15) * CDIM + l4 * 8;
#pragma unroll
    for (int kt = 0; kt < 8; ++kt) {
      ah[kt] = *(const bf16x8*)(qh + rowbase + kt * 32);
      al[kt] = *(const bf16x8*)(ql + rowbase + kt * 32);
    }
  }

  // stage K tile (mt,kt) into kbuf[buf] in frag-linear layout:
  // byte offset = frag*1024 + lane*16 ; lane -> (kgrp=l>>4, m=l&15)
  auto stage = [&](int buf, int mt, int kt) {
#pragma unroll
    for (int ii = 0; ii < 2; ++ii) {
      const int fr = wid * 2 + ii;
      size_t g = ((size_t)b * NDIM + mt * 128 + fr * 16 + l15) * CDIM + kt * 32 + l4 * 8;
      gload16(kh + g, &kbuf[buf][0][fr * 512]);
      gload16(kl + g, &kbuf[buf][1][fr * 512]);
    }
  };

  float M[4], S[4], dval[4];
#pragma unroll
  for (int r = 0; r < 4; ++r) { M[r] = -1e30f; S[r] = 0.f; dval[r] = 0.f; }

  stage(0, 0, 0);
  __syncthreads();
  int cur = 0;

  for (int mt = 0; mt < 8; ++mt) {
    f32x4 acc[8];
#pragma unroll
    for (int f = 0; f < 8; ++f) acc[f] = (f32x4){0.f, 0.f, 0.f, 0.f};

    for (int kt = 0; kt < 8; ++kt) {
      const int tt = mt * 8 + kt;
      if (tt + 1 < 64) stage(cur ^ 1, (tt + 1) >> 3, (tt + 1) & 7);
      const unsigned short* bhp = &kbuf[cur][0][0];
      const unsigned short* blp = &kbuf[cur][1][0];
#pragma unroll
      for (int f = 0; f < 8; ++f) {
        bf16x8 Bh = *(const bf16x8*)(bhp + f * 512 + l * 8);
        bf16x8 Bl = *(const bf16x8*)(blp + f * 512 + l * 8);
        acc[f] = __builtin_amdgcn_mfma_f32_16x16x32_bf16(ah[kt], Bh, acc[f], 0, 0, 0);
        acc[f] = __builtin_amdgcn_mfma_f32_16x16x32_bf16(ah[kt], Bl, acc[f], 0, 0, 0);
        acc[f] = __builtin_amdgcn_mfma_f32_16x16x32_bf16(al[kt], Bh, acc[f], 0, 0, 0);
      }
      __syncthreads();
      cur ^= 1;
    }

    // online softmax over this 128-col tile. C/D: col=l&15, row=l4*4+reg.
    const int nrow = n0 + wid * 16 + l4 * 4;
#pragma unroll
    for (int r = 0; r < 4; ++r) {
      const int n = nrow + r;
      float tm = -1e30f;
#pragma unroll
      for (int f = 0; f < 8; ++f) tm = fmaxf(tm, acc[f][r]);
      tm *= SCALE;
#pragma unroll
      for (int off = 8; off >= 1; off >>= 1) tm = fmaxf(tm, __shfl_xor(tm, off));
      const float Mn = fmaxf(M[r], tm);
      float ps = 0.f;
#pragma unroll
      for (int f = 0; f < 8; ++f) ps += __expf(acc[f][r] * SCALE - Mn);
#pragma unroll
      for (int off = 8; off >= 1; off >>= 1) ps += __shfl_xor(ps, off);
      S[r] = S[r] * __expf(M[r] - Mn) + ps;
      M[r] = Mn;
#pragma unroll
      for (int f = 0; f < 8; ++f)
        if (mt * 128 + f * 16 + l15 == n) dval[r] = acc[f][r] * SCALE;
    }
  }

#pragma unroll
  for (int r = 0; r < 4; ++r) {
    const int n = n0 + wid * 16 + l4 * 4 + r;
    if ((n & 15) == l15)
      outp[(size_t)b * NDIM + n] = __expf(dval[r] - M[r]) / S[r];
  }
}

extern "C" void kernel_launch(void* const* d_in, const int* in_sizes, int n_in,
                              void* d_out, int out_size, void* d_ws, size_t ws_size,
                              hipStream_t stream) {
  (void)in_sizes; (void)n_in; (void)out_size; (void)ws_size;
  const float* x     = (const float*)d_in[0];
  const float* y     = (const float*)d_in[1];
  const float* gamma = (const float*)d_in[2];
  const float* beta  = (const float*)d_in[3];
  const float* Wq    = (const float*)d_in[4];
  const float* Wk    = (const float*)d_in[5];
  const float* bq    = (const float*)d_in[6];
  const float* bk    = (const float*)d_in[7];
  float* out = (float*)d_out;
  float* ws  = (float*)d_ws;

  float* st = ws;                                        // 4*BN floats
  unsigned short* planes = (unsigned short*)(ws + 4 * BN);

  stats_k<<<256, 256, 0, stream>>>(x, y, st);

  dim3 g2(NDIM / 128, CDIM / 128, BATCH * 2);
  proj_k<<<g2, 256, 0, stream>>>(x, y, gamma, beta, Wq, Wk, bq, bk, st, planes);

  attn_k<<<512, 256, 0, stream>>>(planes, out);
}

// Round 3
// 222.119 us; speedup vs baseline: 2.3643x; 1.3636x over previous
//
#include <hip/hip_runtime.h>
#include <math.h>

#define BATCH 32
#define CDIM  256
#define NDIM  1024
#define BN    (BATCH * NDIM)               // 32768
#define BNC   ((size_t)BATCH * NDIM * CDIM)
#define LN_EPSF 1e-5f
#define SCALE 0.0625f

typedef __attribute__((ext_vector_type(8))) __bf16 bf16x8;
typedef __attribute__((ext_vector_type(4))) float f32x4;
typedef __attribute__((ext_vector_type(4))) unsigned short ushort4v;

static __device__ __forceinline__ unsigned short f2bf(float f) {
  unsigned u = __float_as_uint(f);
  unsigned r = (u + 0x7FFFu + ((u >> 16) & 1u)) >> 16;   // RNE
  return (unsigned short)r;
}
static __device__ __forceinline__ float bf2f(unsigned short h) {
  return __uint_as_float(((unsigned)h) << 16);
}
static __device__ __forceinline__ void gload16(const void* g, void* l) {
  __builtin_amdgcn_global_load_lds((const __attribute__((address_space(1))) void*)g,
                                   (__attribute__((address_space(3))) void*)l, 16, 0, 0);
}

// ---------------------------------------------------------------------------
// ws layout:
//   ushort wp[4*65536]     : Whq, Wlq, Whk, Wlk   each [co][c]   (512 KB)
//   ushort planes[4*BNC]   : qh, ql, kh, kl       each [B][N][C] (256 MB)
// ---------------------------------------------------------------------------

__global__ __launch_bounds__(256) void wsplit_k(const float* __restrict__ Wq,
                                                const float* __restrict__ Wk,
                                                unsigned short* __restrict__ wp) {
  int idx = blockIdx.x * 256 + threadIdx.x;   // 0 .. 65535
  float vq = Wq[idx];
  unsigned short hq = f2bf(vq);
  wp[idx] = hq;
  wp[65536 + idx] = f2bf(vq - bf2f(hq));
  float vk = Wk[idx];
  unsigned short hk = f2bf(vk);
  wp[131072 + idx] = hk;
  wp[196608 + idx] = f2bf(vk - bf2f(hk));
}

// Fused: load x-slice -> stats -> LN -> split-bf16 -> 3-term MFMA proj ->
// split hi/lo epilogue to planes[B][N][C].
// grid: (NDIM/64, BATCH*2). 256 threads (4 waves). Block tile: 256co x 64n.
__global__ __launch_bounds__(256) void proj_k(const float* __restrict__ x,
                                              const float* __restrict__ y,
                                              const float* __restrict__ gamma,
                                              const float* __restrict__ beta,
                                              const float* __restrict__ bq,
                                              const float* __restrict__ bk,
                                              const unsigned short* __restrict__ wp,
                                              unsigned short* __restrict__ planes) {
  __shared__ unsigned short Lh[64][264];   // padded stride: 528B = 132 words = 4 mod 32
  __shared__ unsigned short Ll[64][264];
  __shared__ float psum[16][64], psq[16][64];
  __shared__ float mu[64], ri[64], gl[CDIM], bl[CDIM], bias_s[CDIM];

  const int t = threadIdx.x;
  const int bz = blockIdx.y;
  const int b = bz >> 1, which = bz & 1;
  const int n0 = blockIdx.x * 64;
  const float* src = which ? y : x;

  gl[t] = gamma[t];
  bl[t] = beta[t];
  bias_s[t] = (which ? bk : bq)[t];

  // ---- phase 1: x slice -> registers (thread: 4 n via float4, 16 c) ----
  const int nq = (t & 15) * 4;      // n offset (4 consecutive)
  const int cs = (t >> 4) * 16;     // 16 c's
  float4 xr[16];
#pragma unroll
  for (int i = 0; i < 16; ++i)
    xr[i] = *(const float4*)(src + ((size_t)b * CDIM + cs + i) * NDIM + n0 + nq);

  // ---- phase 2: stats ----
  {
    float s[4] = {0.f, 0.f, 0.f, 0.f}, q[4] = {0.f, 0.f, 0.f, 0.f};
#pragma unroll
    for (int i = 0; i < 16; ++i) {
      float v0 = xr[i].x, v1 = xr[i].y, v2 = xr[i].z, v3 = xr[i].w;
      s[0] += v0; q[0] += v0 * v0;
      s[1] += v1; q[1] += v1 * v1;
      s[2] += v2; q[2] += v2 * v2;
      s[3] += v3; q[3] += v3 * v3;
    }
#pragma unroll
    for (int j = 0; j < 4; ++j) {
      psum[t >> 4][nq + j] = s[j];
      psq[t >> 4][nq + j] = q[j];
    }
  }
  __syncthreads();
  if (t < 64) {
    float S = 0.f, Q = 0.f;
#pragma unroll
    for (int s16 = 0; s16 < 16; ++s16) { S += psum[s16][t]; Q += psq[s16][t]; }
    float m = S * (1.f / CDIM);
    mu[t] = m;
    ri[t] = rsqrtf(fmaxf(Q * (1.f / CDIM) - m * m, 0.f) + LN_EPSF);
  }
  __syncthreads();

  // ---- phase 3: LN + split -> LDS [n][c] hi/lo ----
  {
    float mj[4], rj[4];
#pragma unroll
    for (int j = 0; j < 4; ++j) { mj[j] = mu[nq + j]; rj[j] = ri[nq + j]; }
#pragma unroll
    for (int k = 0; k < 8; ++k) {
      const int c0 = cs + 2 * k, c1 = c0 + 1;
      const float g0 = gl[c0], b0 = bl[c0], g1 = gl[c1], b1 = bl[c1];
      const float u0[4] = {xr[2 * k].x, xr[2 * k].y, xr[2 * k].z, xr[2 * k].w};
      const float u1[4] = {xr[2 * k + 1].x, xr[2 * k + 1].y, xr[2 * k + 1].z, xr[2 * k + 1].w};
#pragma unroll
      for (int j = 0; j < 4; ++j) {
        float v0 = (u0[j] - mj[j]) * rj[j] * g0 + b0;
        float v1 = (u1[j] - mj[j]) * rj[j] * g1 + b1;
        unsigned short h0 = f2bf(v0), h1 = f2bf(v1);
        unsigned short e0 = f2bf(v0 - bf2f(h0)), e1 = f2bf(v1 - bf2f(h1));
        *(unsigned*)&Lh[nq + j][c0] = ((unsigned)h1 << 16) | h0;
        *(unsigned*)&Ll[nq + j][c0] = ((unsigned)e1 << 16) | e0;
      }
    }
  }
  __syncthreads();

  // ---- phase 4: MFMA. wave w: co in [w*64, w*64+64), all 64 n ----
  const int w = t >> 6, l = t & 63;
  const int l15 = l & 15, l4 = l >> 4;
  const int co_base = w * 64;
  const unsigned short* Wh = wp + (size_t)which * 131072;
  const unsigned short* Wl = Wh + 65536;

  f32x4 acc[4][4];
#pragma unroll
  for (int i = 0; i < 4; ++i)
#pragma unroll
    for (int j = 0; j < 4; ++j) acc[i][j] = (f32x4){0.f, 0.f, 0.f, 0.f};

#pragma unroll
  for (int kt = 0; kt < 8; ++kt) {
    const int c0 = kt * 32;
    bf16x8 Ah[4], Al[4], Bh[4], Bl[4];
#pragma unroll
    for (int i = 0; i < 4; ++i) {
      size_t off = (size_t)(co_base + i * 16 + l15) * CDIM + c0 + l4 * 8;
      Ah[i] = *(const bf16x8*)(Wh + off);
      Al[i] = *(const bf16x8*)(Wl + off);
    }
#pragma unroll
    for (int j = 0; j < 4; ++j) {
      Bh[j] = *(const bf16x8*)&Lh[j * 16 + l15][c0 + l4 * 8];
      Bl[j] = *(const bf16x8*)&Ll[j * 16 + l15][c0 + l4 * 8];
    }
#pragma unroll
    for (int i = 0; i < 4; ++i)
#pragma unroll
      for (int j = 0; j < 4; ++j) {
        acc[i][j] = __builtin_amdgcn_mfma_f32_16x16x32_bf16(Ah[i], Bh[j], acc[i][j], 0, 0, 0);
        acc[i][j] = __builtin_amdgcn_mfma_f32_16x16x32_bf16(Ah[i], Bl[j], acc[i][j], 0, 0, 0);
        acc[i][j] = __builtin_amdgcn_mfma_f32_16x16x32_bf16(Al[i], Bh[j], acc[i][j], 0, 0, 0);
      }
  }

  // ---- epilogue: + bias, split hi/lo, write planes [b][n][co] ----
  unsigned short* ph = planes + (size_t)which * (2 * BNC);
  unsigned short* pl = ph + BNC;
#pragma unroll
  for (int i = 0; i < 4; ++i) {
    const int co4 = co_base + i * 16 + l4 * 4;
    float bias4[4];
#pragma unroll
    for (int r = 0; r < 4; ++r) bias4[r] = bias_s[co4 + r];
#pragma unroll
    for (int j = 0; j < 4; ++j) {
      size_t base = ((size_t)b * NDIM + n0 + j * 16 + l15) * CDIM + co4;
      ushort4v hs, ls;
#pragma unroll
      for (int r = 0; r < 4; ++r) {
        float v = acc[i][j][r] + bias4[r];
        unsigned short h = f2bf(v);
        hs[r] = h;
        ls[r] = f2bf(v - bf2f(h));
      }
      *(ushort4v*)(ph + base) = hs;
      *(ushort4v*)(pl + base) = ls;
    }
  }
}

// attn: scores = Q K^T via 3-term split-bf16 MFMA, online softmax, diag out.
// 1D grid 512 blocks (batch-grouped XCD swizzle), 4 waves, 16 rows/wave.
__global__ __launch_bounds__(256) void attn_k(const unsigned short* __restrict__ planes,
                                              float* __restrict__ outp) {
  const unsigned short* qh = planes;
  const unsigned short* ql = planes + BNC;
  const unsigned short* kh = planes + 2 * BNC;
  const unsigned short* kl = planes + 3 * BNC;
  __shared__ unsigned short kbuf[2][2][4096];   // [dbuf][hi/lo][8KB]

  const int p = blockIdx.x;                      // 0..511
  const int b = (p & 7) * 4 + ((p >> 3) & 3);    // same-batch blocks -> same XCD
  const int n0 = (p >> 5) * 64;
  const int t = threadIdx.x;
  const int wid = t >> 6;
  const int l = t & 63;
  const int l15 = l & 15, l4 = l >> 4;

  bf16x8 ah[8], al[8];
  {
    size_t rowbase = ((size_t)b * NDIM + n0 + wid * 16 + l15) * CDIM + l4 * 8;
#pragma unroll
    for (int kt = 0; kt < 8; ++kt) {
      ah[kt] = *(const bf16x8*)(qh + rowbase + kt * 32);
      al[kt] = *(const bf16x8*)(ql + rowbase + kt * 32);
    }
  }

  auto stage = [&](int buf, int mt, int kt) {
#pragma unroll
    for (int ii = 0; ii < 2; ++ii) {
      const int fr = wid * 2 + ii;
      size_t g = ((size_t)b * NDIM + mt * 128 + fr * 16 + l15) * CDIM + kt * 32 + l4 * 8;
      gload16(kh + g, &kbuf[buf][0][fr * 512]);
      gload16(kl + g, &kbuf[buf][1][fr * 512]);
    }
  };

  float M[4], S[4], dval[4];
#pragma unroll
  for (int r = 0; r < 4; ++r) { M[r] = -1e30f; S[r] = 0.f; dval[r] = 0.f; }

  stage(0, 0, 0);
  __syncthreads();
  int cur = 0;

  for (int mt = 0; mt < 8; ++mt) {
    f32x4 acc[8];
#pragma unroll
    for (int f = 0; f < 8; ++f) acc[f] = (f32x4){0.f, 0.f, 0.f, 0.f};

    for (int kt = 0; kt < 8; ++kt) {
      const int tt = mt * 8 + kt;
      if (tt + 1 < 64) stage(cur ^ 1, (tt + 1) >> 3, (tt + 1) & 7);
      const unsigned short* bhp = &kbuf[cur][0][0];
      const unsigned short* blp = &kbuf[cur][1][0];
#pragma unroll
      for (int f = 0; f < 8; ++f) {
        bf16x8 Bh = *(const bf16x8*)(bhp + f * 512 + l * 8);
        bf16x8 Bl = *(const bf16x8*)(blp + f * 512 + l * 8);
        acc[f] = __builtin_amdgcn_mfma_f32_16x16x32_bf16(ah[kt], Bh, acc[f], 0, 0, 0);
        acc[f] = __builtin_amdgcn_mfma_f32_16x16x32_bf16(ah[kt], Bl, acc[f], 0, 0, 0);
        acc[f] = __builtin_amdgcn_mfma_f32_16x16x32_bf16(al[kt], Bh, acc[f], 0, 0, 0);
      }
      __syncthreads();
      cur ^= 1;
    }

    const int nrow = n0 + wid * 16 + l4 * 4;
#pragma unroll
    for (int r = 0; r < 4; ++r) {
      const int n = nrow + r;
      float tm = -1e30f;
#pragma unroll
      for (int f = 0; f < 8; ++f) tm = fmaxf(tm, acc[f][r]);
      tm *= SCALE;
#pragma unroll
      for (int off = 8; off >= 1; off >>= 1) tm = fmaxf(tm, __shfl_xor(tm, off));
      const float Mn = fmaxf(M[r], tm);
      float ps = 0.f;
#pragma unroll
      for (int f = 0; f < 8; ++f) ps += __expf(acc[f][r] * SCALE - Mn);
#pragma unroll
      for (int off = 8; off >= 1; off >>= 1) ps += __shfl_xor(ps, off);
      S[r] = S[r] * __expf(M[r] - Mn) + ps;
      M[r] = Mn;
#pragma unroll
      for (int f = 0; f < 8; ++f)
        if (mt * 128 + f * 16 + l15 == n) dval[r] = acc[f][r] * SCALE;
    }
  }

#pragma unroll
  for (int r = 0; r < 4; ++r) {
    const int n = n0 + wid * 16 + l4 * 4 + r;
    if ((n & 15) == l15)
      outp[(size_t)b * NDIM + n] = __expf(dval[r] - M[r]) / S[r];
  }
}

extern "C" void kernel_launch(void* const* d_in, const int* in_sizes, int n_in,
                              void* d_out, int out_size, void* d_ws, size_t ws_size,
                              hipStream_t stream) {
  (void)in_sizes; (void)n_in; (void)out_size; (void)ws_size;
  const float* x     = (const float*)d_in[0];
  const float* y     = (const float*)d_in[1];
  const float* gamma = (const float*)d_in[2];
  const float* beta  = (const float*)d_in[3];
  const float* Wq    = (const float*)d_in[4];
  const float* Wk    = (const float*)d_in[5];
  const float* bq    = (const float*)d_in[6];
  const float* bk    = (const float*)d_in[7];
  float* out = (float*)d_out;

  unsigned short* wp = (unsigned short*)d_ws;
  unsigned short* planes = wp + 262144;

  wsplit_k<<<256, 256, 0, stream>>>(Wq, Wk, wp);

  dim3 g2(NDIM / 64, BATCH * 2);
  proj_k<<<g2, 256, 0, stream>>>(x, y, gamma, beta, bq, bk, wp, planes);

  attn_k<<<512, 256, 0, stream>>>(planes, out);
}